// Round 1
// baseline (13065.392 us; speedup 1.0000x reference)
//
#include <hip/hip_runtime.h>
#include <cstdint>
#include <cstddef>

// Problem constants (from reference)
constexpr int Dm   = 1024;   // model dim
constexpr int NH   = 16;     // heads
constexpr int DK   = 64;     // head dim
constexpr int Bb   = 4;      // batch
constexpr int TLEN = 512;    // tgt len
constexpr int SLEN = 256;    // src len
constexpr int NL   = 8;      // layers
constexpr int FFd  = 4096;   // ffn dim
constexpr int Vv   = 32000;  // vocab

// ---------------------------------------------------------------------------
// Positional encoding value for (pos s, channel d), D = 1024
__device__ __forceinline__ float pe_val(int s, int d) {
  float e = -(float)(d & ~1) * (9.210340371976184f / (float)Dm);
  float freq = expf(e);
  float ang = (float)s * freq;
  return (d & 1) ? cosf(ang) : sinf(ang);
}

__global__ __launch_bounds__(256) void embed_pe_kernel(
    const float* __restrict__ emb, const int* __restrict__ tgt,
    float* __restrict__ x) {
  int idx = blockIdx.x * 256 + threadIdx.x;   // < Bb*TLEN*Dm
  int bs = idx >> 10;                          // b*TLEN + s
  int d  = idx & 1023;
  int s  = bs & (TLEN - 1);
  int tok = tgt[bs];
  x[idx] = emb[(size_t)tok * Dm + d] + pe_val(s, d);
}

__global__ __launch_bounds__(256) void src_pe_kernel(
    const float* __restrict__ src, float* __restrict__ enc) {
  int idx = blockIdx.x * 256 + threadIdx.x;   // < Bb*SLEN*Dm
  int d = idx & 1023;
  int s = (idx >> 10) & (SLEN - 1);
  enc[idx] = src[idx] + pe_val(s, d);
}

// ---------------------------------------------------------------------------
// Block-wide reduction helper. op: 0 = sum, 1 = max. red must hold >= 4 floats.
__device__ __forceinline__ float block_reduce(float v, int op, float* red) {
#pragma unroll
  for (int off = 32; off > 0; off >>= 1) {
    float o = __shfl_down(v, off, 64);
    v = op ? fmaxf(v, o) : (v + o);
  }
  int tid = threadIdx.x;
  int nw = blockDim.x >> 6;   // waves per block
  if ((tid & 63) == 0) red[tid >> 6] = v;
  __syncthreads();
  float r = red[0];
  for (int i = 1; i < nw; i++) r = op ? fmaxf(r, red[i]) : (r + red[i]);
  __syncthreads();            // make red reusable
  return r;
}

// ---------------------------------------------------------------------------
// Tiled fp32 GEMM body: C[M,N] = A[M,K] @ B[K,N] + bias[N] (optional relu).
// BM x BN tile, K-tile 16, 256 threads, (BM/16)x(BN/16) accum per thread.
// LDS padded +4: all LDS access patterns verified <=2-way bank aliasing (free).
template<int BM, int BN>
__device__ __forceinline__ void gemm_body(
    const float* __restrict__ A, const float* __restrict__ B,
    const float* __restrict__ bias, float* __restrict__ C,
    int M, int N, int K, int relu,
    float (&As)[16][BM + 4], float (&Bs)[16][BN + 4]) {
  constexpr int TM = BM / 16, TN = BN / 16;
  constexpr int RG = TM / 4, CG = TN / 4;   // 64-row / 64-col groups
  int tid = threadIdx.x;
  int tx = tid & 15, ty = tid >> 4;
  int col0 = blockIdx.x * BN;
  int row0 = blockIdx.y * BM;
  if (row0 >= M) return;                     // inactive z-merged block
  int ar = tid >> 2, ac = (tid & 3) << 2;    // A stage: row ar(+64), cols ac..ac+3
  int br = tid >> 4, bc = (tid & 15) << 2;   // B stage: row br, cols bc(+64)
  const float* Ap = A + (size_t)(row0 + ar) * K + ac;
  const float* Bp = B + (size_t)br * N + col0 + bc;
  float acc[TM][TN] = {};
  for (int k0 = 0; k0 < K; k0 += 16) {
#pragma unroll
    for (int g = 0; g < RG; ++g) {
      float4 a4 = *(const float4*)(Ap + (size_t)(g * 64) * K + k0);
      As[ac + 0][g * 64 + ar] = a4.x;
      As[ac + 1][g * 64 + ar] = a4.y;
      As[ac + 2][g * 64 + ar] = a4.z;
      As[ac + 3][g * 64 + ar] = a4.w;
    }
#pragma unroll
    for (int h = 0; h < CG; ++h) {
      float4 b4 = *(const float4*)(Bp + (size_t)k0 * N + h * 64);
      *(float4*)&Bs[br][bc + h * 64] = b4;
    }
    __syncthreads();
#pragma unroll
    for (int kk = 0; kk < 16; ++kk) {
      float a[TM], b[TN];
#pragma unroll
      for (int g = 0; g < RG; ++g) {
        float4 t = *(const float4*)&As[kk][g * 64 + ty * 4];
        a[g * 4 + 0] = t.x; a[g * 4 + 1] = t.y;
        a[g * 4 + 2] = t.z; a[g * 4 + 3] = t.w;
      }
#pragma unroll
      for (int h = 0; h < CG; ++h) {
        float4 t = *(const float4*)&Bs[kk][h * 64 + tx * 4];
        b[h * 4 + 0] = t.x; b[h * 4 + 1] = t.y;
        b[h * 4 + 2] = t.z; b[h * 4 + 3] = t.w;
      }
#pragma unroll
      for (int i = 0; i < TM; ++i)
#pragma unroll
        for (int j = 0; j < TN; ++j)
          acc[i][j] = fmaf(a[i], b[j], acc[i][j]);
    }
    __syncthreads();
  }
  // epilogue
#pragma unroll
  for (int h = 0; h < CG; ++h) {
    float4 bs4 = *(const float4*)(bias + col0 + h * 64 + tx * 4);
#pragma unroll
    for (int g = 0; g < RG; ++g) {
#pragma unroll
      for (int i = 0; i < 4; ++i) {
        int row = row0 + g * 64 + ty * 4 + i;
        float4 o;
        o.x = acc[g * 4 + i][h * 4 + 0] + bs4.x;
        o.y = acc[g * 4 + i][h * 4 + 1] + bs4.y;
        o.z = acc[g * 4 + i][h * 4 + 2] + bs4.z;
        o.w = acc[g * 4 + i][h * 4 + 3] + bs4.w;
        if (relu) {
          o.x = fmaxf(o.x, 0.f); o.y = fmaxf(o.y, 0.f);
          o.z = fmaxf(o.z, 0.f); o.w = fmaxf(o.w, 0.f);
        }
        *(float4*)(C + (size_t)row * N + col0 + h * 64 + tx * 4) = o;
      }
    }
  }
}

template<int BM, int BN>
__global__ __launch_bounds__(256) void gemm_t(
    const float* __restrict__ A, const float* __restrict__ B,
    const float* __restrict__ bias, float* __restrict__ C,
    int M, int N, int K, int relu) {
  __shared__ float As[16][BM + 4];
  __shared__ float Bs[16][BN + 4];
  gemm_body<BM, BN>(A, B, bias, C, M, N, K, relu, As, Bs);
}

// Three GEMMs sharing N,K fused across blockIdx.z (fills the chip for the
// Q/K/V projections whose individual grids are only 64-128 workgroups).
__global__ __launch_bounds__(256) void gemm3_kernel(
    const float* __restrict__ A0, const float* __restrict__ A1,
    const float* __restrict__ A2,
    const float* __restrict__ B0, const float* __restrict__ B1,
    const float* __restrict__ B2,
    const float* __restrict__ b0, const float* __restrict__ b1,
    const float* __restrict__ b2,
    float* __restrict__ C0, float* __restrict__ C1, float* __restrict__ C2,
    int M0, int M1, int M2, int N, int K) {
  __shared__ float As[16][132];
  __shared__ float Bs[16][132];
  int z = blockIdx.z;
  const float* A = (z == 0) ? A0 : (z == 1) ? A1 : A2;
  const float* B = (z == 0) ? B0 : (z == 1) ? B1 : B2;
  const float* bi = (z == 0) ? b0 : (z == 1) ? b1 : b2;
  float* C = (z == 0) ? C0 : (z == 1) ? C1 : C2;
  int M = (z == 0) ? M0 : (z == 1) ? M1 : M2;
  gemm_body<128, 128>(A, B, bi, C, M, N, K, 0, As, Bs);
}

// ---------------------------------------------------------------------------
// scores[bh, q, k] = scale * dot(Q[b,q,h*64:...], K[b,k,h*64:...])
// grid: (Sk/64, Sq/64, B*NH)
__global__ __launch_bounds__(256) void attn_scores_kernel(
    const float* __restrict__ Q, const float* __restrict__ Km,
    float* __restrict__ S, int Sq, int Sk, float scale) {
  __shared__ float Qs[16][64];
  __shared__ float Ks[16][64];
  int tid = threadIdx.x;
  int tx4 = (tid & 15) << 2;
  int ty4 = (tid >> 4) << 2;
  int bh = blockIdx.z;
  int b = bh >> 4, h = bh & 15;
  int k0g = blockIdx.x << 6;
  int q0g = blockIdx.y << 6;
  const float* Qb = Q + (size_t)b * Sq * Dm + (size_t)h * DK;
  const float* Kb = Km + (size_t)b * Sk * Dm + (size_t)h * DK;
  float* Sb = S + (size_t)bh * Sq * Sk;
  int ar = tid >> 2, ac = (tid & 3) << 2;
  float acc[4][4] = {{0.f}};
  for (int d0 = 0; d0 < DK; d0 += 16) {
    float4 a4 = *(const float4*)(Qb + (size_t)(q0g + ar) * Dm + d0 + ac);
    float4 b4 = *(const float4*)(Kb + (size_t)(k0g + ar) * Dm + d0 + ac);
    Qs[ac + 0][ar] = a4.x; Qs[ac + 1][ar] = a4.y;
    Qs[ac + 2][ar] = a4.z; Qs[ac + 3][ar] = a4.w;
    Ks[ac + 0][ar] = b4.x; Ks[ac + 1][ar] = b4.y;
    Ks[ac + 2][ar] = b4.z; Ks[ac + 3][ar] = b4.w;
    __syncthreads();
#pragma unroll
    for (int kk = 0; kk < 16; ++kk) {
      float4 a = *(const float4*)&Qs[kk][ty4];
      float4 b = *(const float4*)&Ks[kk][tx4];
      float av[4] = {a.x, a.y, a.z, a.w};
      float bv[4] = {b.x, b.y, b.z, b.w};
#pragma unroll
      for (int i = 0; i < 4; ++i)
#pragma unroll
        for (int j = 0; j < 4; ++j)
          acc[i][j] = fmaf(av[i], bv[j], acc[i][j]);
    }
    __syncthreads();
  }
#pragma unroll
  for (int i = 0; i < 4; ++i) {
    float4 o;
    o.x = acc[i][0] * scale; o.y = acc[i][1] * scale;
    o.z = acc[i][2] * scale; o.w = acc[i][3] * scale;
    *(float4*)(Sb + (size_t)(q0g + ty4 + i) * Sk + k0g + tx4) = o;
  }
}

// ---------------------------------------------------------------------------
// In-place masked softmax over last dim. grid: B*NH*TLEN rows.
// causal=1: self-attn mask = (tgt[b,q] != 0) && (k <= q); causal=0: no mask.
__global__ __launch_bounds__(256) void softmax_mask_kernel(
    float* __restrict__ S, const int* __restrict__ tgt, int Sk, int causal) {
  __shared__ float buf[TLEN];
  __shared__ float red[4];
  int r = blockIdx.x;            // ((b*NH + h)*TLEN + q)
  int q = r & (TLEN - 1);
  int b = r >> 13;               // / (NH*TLEN)
  float* row = S + (size_t)r * Sk;
  int tid = threadIdx.x;
  bool row_valid = true;
  if (causal) row_valid = (tgt[b * TLEN + q] != 0);
  float lmax = -3.4e38f;
  for (int i = tid; i < Sk; i += 256) {
    float v = row[i];
    if (causal && (!row_valid || i > q)) v = -1e9f;
    buf[i] = v;
    lmax = fmaxf(lmax, v);
  }
  float gmax = block_reduce(lmax, 1, red);
  float lsum = 0.f;
  for (int i = tid; i < Sk; i += 256) {
    float e = __expf(buf[i] - gmax);
    buf[i] = e;
    lsum += e;
  }
  float gsum = block_reduce(lsum, 0, red);
  float inv = 1.0f / gsum;
  for (int i = tid; i < Sk; i += 256) row[i] = buf[i] * inv;
}

// ---------------------------------------------------------------------------
// O[b, q, h*64+n] = sum_k P[bh, q, k] * V[b, k, h*64+n]
// grid: (Sq/64, B*NH). N = 64 (one tile).
__global__ __launch_bounds__(256) void attn_pv_kernel(
    const float* __restrict__ P, const float* __restrict__ V,
    float* __restrict__ O, int Sq, int Sk) {
  __shared__ float Ps[16][64];
  __shared__ float Vs[16][64];
  int tid = threadIdx.x;
  int tx4 = (tid & 15) << 2;
  int ty4 = (tid >> 4) << 2;
  int bh = blockIdx.y;
  int b = bh >> 4, h = bh & 15;
  int q0 = blockIdx.x << 6;
  const float* Pb = P + (size_t)bh * Sq * Sk;
  const float* Vb = V + (size_t)b * Sk * Dm + (size_t)h * DK;
  float* Ob = O + (size_t)b * Sq * Dm + (size_t)h * DK;
  int ar = tid >> 2, ac = (tid & 3) << 2;
  int br = tid >> 4;
  float acc[4][4] = {{0.f}};
  for (int k0 = 0; k0 < Sk; k0 += 16) {
    float4 a4 = *(const float4*)(Pb + (size_t)(q0 + ar) * Sk + k0 + ac);
    float4 b4 = *(const float4*)(Vb + (size_t)(k0 + br) * Dm + tx4);
    Ps[ac + 0][ar] = a4.x; Ps[ac + 1][ar] = a4.y;
    Ps[ac + 2][ar] = a4.z; Ps[ac + 3][ar] = a4.w;
    *(float4*)&Vs[br][tx4] = b4;
    __syncthreads();
#pragma unroll
    for (int kk = 0; kk < 16; ++kk) {
      float4 a = *(const float4*)&Ps[kk][ty4];
      float4 b = *(const float4*)&Vs[kk][tx4];
      float av[4] = {a.x, a.y, a.z, a.w};
      float bv[4] = {b.x, b.y, b.z, b.w};
#pragma unroll
      for (int i = 0; i < 4; ++i)
#pragma unroll
        for (int j = 0; j < 4; ++j)
          acc[i][j] = fmaf(av[i], bv[j], acc[i][j]);
    }
    __syncthreads();
  }
#pragma unroll
  for (int i = 0; i < 4; ++i) {
    float4 o;
    o.x = acc[i][0]; o.y = acc[i][1]; o.z = acc[i][2]; o.w = acc[i][3];
    *(float4*)(Ob + (size_t)(q0 + ty4 + i) * Dm + tx4) = o;
  }
}

// ---------------------------------------------------------------------------
// x = LayerNorm(x + a) * g + b   (row = one token, D = 1024)
__global__ __launch_bounds__(256) void add_ln_kernel(
    float* __restrict__ x, const float* __restrict__ a,
    const float* __restrict__ g, const float* __restrict__ be) {
  __shared__ float buf[Dm];
  __shared__ float red[4];
  int r = blockIdx.x;
  float* xr = x + (size_t)r * Dm;
  const float* ar = a + (size_t)r * Dm;
  int tid = threadIdx.x;
  float ls = 0.f;
  for (int i = tid; i < Dm; i += 256) {
    float v = xr[i] + ar[i];
    buf[i] = v;
    ls += v;
  }
  float mu = block_reduce(ls, 0, red) * (1.0f / Dm);
  float lv = 0.f;
  for (int i = tid; i < Dm; i += 256) {
    float d = buf[i] - mu;
    lv += d * d;
  }
  float var = block_reduce(lv, 0, red) * (1.0f / Dm);
  float inv = rsqrtf(var + 1e-5f);
  for (int i = tid; i < Dm; i += 256)
    xr[i] = (buf[i] - mu) * inv * g[i] + be[i];
}

// ---------------------------------------------------------------------------
extern "C" void kernel_launch(void* const* d_in, const int* in_sizes, int n_in,
                              void* d_out, int out_size, void* d_ws, size_t ws_size,
                              hipStream_t stream) {
  // setup_inputs() dict order:
  const float* src  = (const float*)d_in[0];
  const int*   tgt  = (const int*)  d_in[1];
  const float* emb  = (const float*)d_in[2];
  const float* fc_w = (const float*)d_in[3];
  const float* fc_b = (const float*)d_in[4];
  const float* sa_wq = (const float*)d_in[5];
  const float* sa_bq = (const float*)d_in[6];
  const float* sa_wk = (const float*)d_in[7];
  const float* sa_bk = (const float*)d_in[8];
  const float* sa_wv = (const float*)d_in[9];
  const float* sa_bv = (const float*)d_in[10];
  const float* sa_wo = (const float*)d_in[11];
  const float* sa_bo = (const float*)d_in[12];
  const float* ca_wq = (const float*)d_in[13];
  const float* ca_bq = (const float*)d_in[14];
  const float* ca_wk = (const float*)d_in[15];
  const float* ca_bk = (const float*)d_in[16];
  const float* ca_wv = (const float*)d_in[17];
  const float* ca_bv = (const float*)d_in[18];
  const float* ca_wo = (const float*)d_in[19];
  const float* ca_bo = (const float*)d_in[20];
  const float* w1   = (const float*)d_in[21];
  const float* b1   = (const float*)d_in[22];
  const float* w2   = (const float*)d_in[23];
  const float* b2   = (const float*)d_in[24];
  const float* n1g  = (const float*)d_in[25];
  const float* n2g  = (const float*)d_in[26];
  const float* n3g  = (const float*)d_in[27];
  const float* n1b  = (const float*)d_in[28];
  const float* n2b  = (const float*)d_in[29];
  const float* n3b  = (const float*)d_in[30];
  float* out = (float*)d_out;

  // Workspace carve-up (floats)
  float* ws = (float*)d_ws;
  const size_t encN   = (size_t)Bb * SLEN * Dm;   // 1M
  const size_t xN     = (size_t)Bb * TLEN * Dm;   // 2M
  float* enc    = ws;
  float* x      = enc + encN;
  float* qb     = x + xN;
  float* kb     = qb + xN;
  float* vb     = kb + xN;
  float* attnb  = vb + xN;
  float* projb  = attnb + xN;
  float* ffh    = projb + xN;                     // 2048*4096
  float* scores = ffh + (size_t)Bb * TLEN * FFd;  // 4*16*512*512

  const int M  = Bb * TLEN;   // 2048 decoder tokens
  const int Me = Bb * SLEN;   // 1024 encoder tokens
  dim3 blk(256);

  embed_pe_kernel<<<(Bb * TLEN * Dm) / 256, blk, 0, stream>>>(emb, tgt, x);
  src_pe_kernel<<<(Bb * SLEN * Dm) / 256, blk, 0, stream>>>(src, enc);

  const float scale = 0.125f;   // 1/sqrt(64)

  for (int l = 0; l < NL; ++l) {
    const size_t wOff = (size_t)l * Dm * Dm;
    const size_t bOff = (size_t)l * Dm;

    // ---- self attention ----
    // Q,K,V projections merged across blockIdx.z: 384 blocks fills the chip
    gemm3_kernel<<<dim3(Dm / 128, M / 128, 3), blk, 0, stream>>>(
        x, x, x,
        sa_wq + wOff, sa_wk + wOff, sa_wv + wOff,
        sa_bq + bOff, sa_bk + bOff, sa_bv + bOff,
        qb, kb, vb, M, M, M, Dm, Dm);
    attn_scores_kernel<<<dim3(TLEN / 64, TLEN / 64, Bb * NH), blk, 0, stream>>>(
        qb, kb, scores, TLEN, TLEN, scale);
    softmax_mask_kernel<<<Bb * NH * TLEN, blk, 0, stream>>>(scores, tgt, TLEN, 1);
    attn_pv_kernel<<<dim3(TLEN / 64, Bb * NH), blk, 0, stream>>>(
        scores, vb, attnb, TLEN, TLEN);
    // O-projection: 64x128 tile -> 256 blocks (128x128 would be only 128)
    gemm_t<64, 128><<<dim3(Dm / 128, M / 64), blk, 0, stream>>>(
        attnb, sa_wo + wOff, sa_bo + bOff, projb, M, Dm, Dm, 0);
    add_ln_kernel<<<M, blk, 0, stream>>>(x, projb, n1g + bOff, n1b + bOff);

    // ---- cross attention ----
    // Q (M=2048, from x) + K,V (M=1024, from enc) merged: 256 active blocks
    gemm3_kernel<<<dim3(Dm / 128, M / 128, 3), blk, 0, stream>>>(
        x, enc, enc,
        ca_wq + wOff, ca_wk + wOff, ca_wv + wOff,
        ca_bq + bOff, ca_bk + bOff, ca_bv + bOff,
        qb, kb, vb, M, Me, Me, Dm, Dm);
    attn_scores_kernel<<<dim3(SLEN / 64, TLEN / 64, Bb * NH), blk, 0, stream>>>(
        qb, kb, scores, TLEN, SLEN, scale);
    softmax_mask_kernel<<<Bb * NH * TLEN, blk, 0, stream>>>(scores, tgt, SLEN, 0);
    attn_pv_kernel<<<dim3(TLEN / 64, Bb * NH), blk, 0, stream>>>(
        scores, vb, attnb, TLEN, SLEN);
    gemm_t<64, 128><<<dim3(Dm / 128, M / 64), blk, 0, stream>>>(
        attnb, ca_wo + wOff, ca_bo + bOff, projb, M, Dm, Dm, 0);
    add_ln_kernel<<<M, blk, 0, stream>>>(x, projb, n2g + bOff, n2b + bOff);

    // ---- feed forward ----
    gemm_t<128, 128><<<dim3(FFd / 128, M / 128), blk, 0, stream>>>(
        x, w1 + (size_t)l * Dm * FFd, b1 + (size_t)l * FFd, ffh, M, FFd, Dm, 1);
    gemm_t<64, 128><<<dim3(Dm / 128, M / 64), blk, 0, stream>>>(
        ffh, w2 + (size_t)l * FFd * Dm, b2 + bOff, projb, M, Dm, FFd, 0);
    add_ln_kernel<<<M, blk, 0, stream>>>(x, projb, n3g + bOff, n3b + bOff);
  }

  // ---- final projection to vocab ----
  gemm_t<128, 128><<<dim3(Vv / 128, M / 128), blk, 0, stream>>>(
      x, fc_w, fc_b, out, M, Vv, Dm, 0);
}

// Round 2
// 5817.625 us; speedup vs baseline: 2.2458x; 2.2458x over previous
//
#include <hip/hip_runtime.h>
#include <cstdint>
#include <cstddef>

// Problem constants (from reference)
constexpr int Dm   = 1024;   // model dim
constexpr int NH   = 16;     // heads
constexpr int DK   = 64;     // head dim
constexpr int Bb   = 4;      // batch
constexpr int TLEN = 512;    // tgt len
constexpr int SLEN = 256;    // src len
constexpr int NL   = 8;      // layers
constexpr int FFd  = 4096;   // ffn dim
constexpr int Vv   = 32000;  // vocab

using f32x4  = __attribute__((ext_vector_type(4))) float;
using bf16x8 = __attribute__((ext_vector_type(8))) short;

// ---------------------------------------------------------------------------
// Positional encoding value for (pos s, channel d), D = 1024
__device__ __forceinline__ float pe_val(int s, int d) {
  float e = -(float)(d & ~1) * (9.210340371976184f / (float)Dm);
  float freq = expf(e);
  float ang = (float)s * freq;
  return (d & 1) ? cosf(ang) : sinf(ang);
}

__global__ __launch_bounds__(256) void embed_pe_kernel(
    const float* __restrict__ emb, const int* __restrict__ tgt,
    float* __restrict__ x) {
  int idx = blockIdx.x * 256 + threadIdx.x;   // < Bb*TLEN*Dm
  int bs = idx >> 10;                          // b*TLEN + s
  int d  = idx & 1023;
  int s  = bs & (TLEN - 1);
  int tok = tgt[bs];
  x[idx] = emb[(size_t)tok * Dm + d] + pe_val(s, d);
}

__global__ __launch_bounds__(256) void src_pe_kernel(
    const float* __restrict__ src, float* __restrict__ enc) {
  int idx = blockIdx.x * 256 + threadIdx.x;   // < Bb*SLEN*Dm
  int d = idx & 1023;
  int s = (idx >> 10) & (SLEN - 1);
  enc[idx] = src[idx] + pe_val(s, d);
}

// ---------------------------------------------------------------------------
// Block-wide reduction helper. op: 0 = sum, 1 = max. red must hold >= 4 floats.
__device__ __forceinline__ float block_reduce(float v, int op, float* red) {
#pragma unroll
  for (int off = 32; off > 0; off >>= 1) {
    float o = __shfl_down(v, off, 64);
    v = op ? fmaxf(v, o) : (v + o);
  }
  int tid = threadIdx.x;
  int nw = blockDim.x >> 6;   // waves per block
  if ((tid & 63) == 0) red[tid >> 6] = v;
  __syncthreads();
  float r = red[0];
  for (int i = 1; i < nw; i++) r = op ? fmaxf(r, red[i]) : (r + red[i]);
  __syncthreads();            // make red reusable
  return r;
}

// ---------------------------------------------------------------------------
// Split-bf16 helpers: x = hi + lo with hi = trunc_bf16(x), lo = bf16(x - hi).
// Packs two f32 into one u32 of 2 bf16 (elements 2p, 2p+1).
__device__ __forceinline__ void cvt_split_pair(float xa, float xb,
                                               unsigned& hi, unsigned& lo) {
  unsigned ua = __float_as_uint(xa), ub = __float_as_uint(xb);
  unsigned ha = ua & 0xFFFF0000u, hb = ub & 0xFFFF0000u;
  hi = (ua >> 16) | hb;
  float la = xa - __uint_as_float(ha);
  float lb = xb - __uint_as_float(hb);
  lo = (__float_as_uint(la) >> 16) | (__float_as_uint(lb) & 0xFFFF0000u);
}

// ---------------------------------------------------------------------------
// Split-bf16 MFMA GEMM: C[M,N] = A[M,K] @ B[K,N] + bias[N] (optional relu).
// Tile BM x 128, K-step 32, 256 threads (4 waves), wave grid WR x WC.
// LDS layout fragment-ready: [kgroup 0..3][row][8 bf16] -> each lane's
// ds_read_b128 is 16B contiguous; 16-lane groups read 256B sequential
// (conflict-free). 3 MFMA per fragment pair (hi*hi + hi*lo + lo*hi) gives
// ~fp32 accuracy (missing lo*lo term ~2^-18 relative).
template<int BM, int WR, int WC>
__device__ __forceinline__ void gemm_mfma_body(
    const float* __restrict__ A, const float* __restrict__ B,
    const float* __restrict__ bias, float* __restrict__ C,
    int M, int N, int K, int relu,
    unsigned short (&Ahi)[4][BM][8], unsigned short (&Alo)[4][BM][8],
    unsigned short (&Bhi)[4][128][8], unsigned short (&Blo)[4][128][8]) {
  constexpr int QM = BM / WR;      // wave quadrant rows
  constexpr int QN = 128 / WC;     // wave quadrant cols
  constexpr int FM = QM / 16;      // m-fragments per wave
  constexpr int FN = QN / 16;      // n-fragments per wave
  constexpr int EA = BM / 8;       // f32 per thread for A staging (8 or 16)
  constexpr int TPR = 32 / EA;     // threads per A row

  int tid = threadIdx.x;
  int col0 = blockIdx.x * 128;
  int row0 = blockIdx.y * BM;
  if (row0 >= M) return;           // inactive z-merged block (uniform per block)
  int lane = tid & 63;
  int wid = tid >> 6;
  int wr = wid / WC, wc = wid % WC;
  int cg = lane >> 4;              // k-group / C row-group
  int cr = lane & 15;              // A row / B col / C col within fragment

  // staging assignments
  int arow = tid / TPR, akq = (tid % TPR) * EA;
  int bkg = tid >> 6,  bc = tid & 63;        // B: kgroup, col (and col+64)

  const float* Ap  = A + (size_t)(row0 + arow) * K + akq;
  const float* Bp0 = B + (size_t)bkg * 8 * N + col0 + bc;

  float aw[EA];
  float bw0[8], bw1[8];

  // prologue: load K-tile 0 into registers
#pragma unroll
  for (int e = 0; e < EA; e += 4)
    *(float4*)&aw[e] = *(const float4*)(Ap + e);
#pragma unroll
  for (int j = 0; j < 8; ++j) {
    bw0[j] = Bp0[(size_t)j * N];
    bw1[j] = Bp0[(size_t)j * N + 64];
  }

  f32x4 acc[FM][FN];
#pragma unroll
  for (int i = 0; i < FM; ++i)
#pragma unroll
    for (int j = 0; j < FN; ++j)
      acc[i][j] = (f32x4){0.f, 0.f, 0.f, 0.f};

  const int NT = K / 32;
  for (int t = 0; t < NT; ++t) {
    // ---- convert staged regs -> LDS (hi/lo bf16) ----
#pragma unroll
    for (int g = 0; g < EA / 8; ++g) {
      unsigned hi2[4], lo2[4];
#pragma unroll
      for (int p = 0; p < 4; ++p)
        cvt_split_pair(aw[g * 8 + p * 2], aw[g * 8 + p * 2 + 1], hi2[p], lo2[p]);
      int kg = (akq >> 3) + g;
      *(uint4*)&Ahi[kg][arow][0] = make_uint4(hi2[0], hi2[1], hi2[2], hi2[3]);
      *(uint4*)&Alo[kg][arow][0] = make_uint4(lo2[0], lo2[1], lo2[2], lo2[3]);
    }
#pragma unroll
    for (int c = 0; c < 2; ++c) {
      const float* bwp = c ? bw1 : bw0;
      unsigned hi2[4], lo2[4];
#pragma unroll
      for (int p = 0; p < 4; ++p)
        cvt_split_pair(bwp[p * 2], bwp[p * 2 + 1], hi2[p], lo2[p]);
      int col = bc + c * 64;
      *(uint4*)&Bhi[bkg][col][0] = make_uint4(hi2[0], hi2[1], hi2[2], hi2[3]);
      *(uint4*)&Blo[bkg][col][0] = make_uint4(lo2[0], lo2[1], lo2[2], lo2[3]);
    }
    __syncthreads();

    // ---- prefetch next K-tile into registers (hides HBM under MFMA) ----
    if (t + 1 < NT) {
      const float* Ap2 = Ap + (t + 1) * 32;
#pragma unroll
      for (int e = 0; e < EA; e += 4)
        *(float4*)&aw[e] = *(const float4*)(Ap2 + e);
      const float* Bp2 = Bp0 + (size_t)(t + 1) * 32 * N;
#pragma unroll
      for (int j = 0; j < 8; ++j) {
        bw0[j] = Bp2[(size_t)j * N];
        bw1[j] = Bp2[(size_t)j * N + 64];
      }
    }

    // ---- fragments + MFMA ----
    bf16x8 bh[FN], bl[FN];
#pragma unroll
    for (int j = 0; j < FN; ++j) {
      bh[j] = *(const bf16x8*)&Bhi[cg][wc * QN + j * 16 + cr][0];
      bl[j] = *(const bf16x8*)&Blo[cg][wc * QN + j * 16 + cr][0];
    }
#pragma unroll
    for (int i = 0; i < FM; ++i) {
      bf16x8 ah = *(const bf16x8*)&Ahi[cg][wr * QM + i * 16 + cr][0];
      bf16x8 al = *(const bf16x8*)&Alo[cg][wr * QM + i * 16 + cr][0];
#pragma unroll
      for (int j = 0; j < FN; ++j) {
        acc[i][j] = __builtin_amdgcn_mfma_f32_16x16x32_bf16(ah, bh[j], acc[i][j], 0, 0, 0);
        acc[i][j] = __builtin_amdgcn_mfma_f32_16x16x32_bf16(ah, bl[j], acc[i][j], 0, 0, 0);
        acc[i][j] = __builtin_amdgcn_mfma_f32_16x16x32_bf16(al, bh[j], acc[i][j], 0, 0, 0);
      }
    }
    __syncthreads();
  }

  // ---- epilogue: C/D layout col = lane&15, row = (lane>>4)*4 + reg ----
#pragma unroll
  for (int j = 0; j < FN; ++j) {
    int col = col0 + wc * QN + j * 16 + cr;
    float bj = bias[col];
#pragma unroll
    for (int i = 0; i < FM; ++i) {
      int rb = row0 + wr * QM + i * 16 + cg * 4;
#pragma unroll
      for (int rr = 0; rr < 4; ++rr) {
        float v = acc[i][j][rr] + bj;
        if (relu) v = fmaxf(v, 0.f);
        C[(size_t)(rb + rr) * N + col] = v;
      }
    }
  }
}

template<int BM, int WR, int WC>
__global__ __launch_bounds__(256, 2) void gemm_mfma_t(
    const float* __restrict__ A, const float* __restrict__ B,
    const float* __restrict__ bias, float* __restrict__ C,
    int M, int N, int K, int relu) {
  __shared__ __align__(16) unsigned short Ahi[4][BM][8];
  __shared__ __align__(16) unsigned short Alo[4][BM][8];
  __shared__ __align__(16) unsigned short Bhi[4][128][8];
  __shared__ __align__(16) unsigned short Blo[4][128][8];
  gemm_mfma_body<BM, WR, WC>(A, B, bias, C, M, N, K, relu, Ahi, Alo, Bhi, Blo);
}

// Three GEMMs sharing N,K fused across blockIdx.z (fills the chip for the
// Q/K/V projections).
__global__ __launch_bounds__(256, 2) void gemm3_mfma(
    const float* __restrict__ A0, const float* __restrict__ A1,
    const float* __restrict__ A2,
    const float* __restrict__ B0, const float* __restrict__ B1,
    const float* __restrict__ B2,
    const float* __restrict__ b0, const float* __restrict__ b1,
    const float* __restrict__ b2,
    float* __restrict__ C0, float* __restrict__ C1, float* __restrict__ C2,
    int M0, int M1, int M2, int N, int K) {
  __shared__ __align__(16) unsigned short Ahi[4][128][8];
  __shared__ __align__(16) unsigned short Alo[4][128][8];
  __shared__ __align__(16) unsigned short Bhi[4][128][8];
  __shared__ __align__(16) unsigned short Blo[4][128][8];
  int z = blockIdx.z;
  const float* A  = (z == 0) ? A0 : (z == 1) ? A1 : A2;
  const float* B  = (z == 0) ? B0 : (z == 1) ? B1 : B2;
  const float* bi = (z == 0) ? b0 : (z == 1) ? b1 : b2;
  float* C        = (z == 0) ? C0 : (z == 1) ? C1 : C2;
  int M           = (z == 0) ? M0 : (z == 1) ? M1 : M2;
  gemm_mfma_body<128, 2, 2>(A, B, bi, C, M, N, K, 0, Ahi, Alo, Bhi, Blo);
}

// ---------------------------------------------------------------------------
// scores[bh, q, k] = scale * dot(Q[b,q,h*64:...], K[b,k,h*64:...])
// grid: (Sk/64, Sq/64, B*NH)
__global__ __launch_bounds__(256) void attn_scores_kernel(
    const float* __restrict__ Q, const float* __restrict__ Km,
    float* __restrict__ S, int Sq, int Sk, float scale) {
  __shared__ float Qs[16][64];
  __shared__ float Ks[16][64];
  int tid = threadIdx.x;
  int tx4 = (tid & 15) << 2;
  int ty4 = (tid >> 4) << 2;
  int bh = blockIdx.z;
  int b = bh >> 4, h = bh & 15;
  int k0g = blockIdx.x << 6;
  int q0g = blockIdx.y << 6;
  const float* Qb = Q + (size_t)b * Sq * Dm + (size_t)h * DK;
  const float* Kb = Km + (size_t)b * Sk * Dm + (size_t)h * DK;
  float* Sb = S + (size_t)bh * Sq * Sk;
  int ar = tid >> 2, ac = (tid & 3) << 2;
  float acc[4][4] = {{0.f}};
  for (int d0 = 0; d0 < DK; d0 += 16) {
    float4 a4 = *(const float4*)(Qb + (size_t)(q0g + ar) * Dm + d0 + ac);
    float4 b4 = *(const float4*)(Kb + (size_t)(k0g + ar) * Dm + d0 + ac);
    Qs[ac + 0][ar] = a4.x; Qs[ac + 1][ar] = a4.y;
    Qs[ac + 2][ar] = a4.z; Qs[ac + 3][ar] = a4.w;
    Ks[ac + 0][ar] = b4.x; Ks[ac + 1][ar] = b4.y;
    Ks[ac + 2][ar] = b4.z; Ks[ac + 3][ar] = b4.w;
    __syncthreads();
#pragma unroll
    for (int kk = 0; kk < 16; ++kk) {
      float4 a = *(const float4*)&Qs[kk][ty4];
      float4 b = *(const float4*)&Ks[kk][tx4];
      float av[4] = {a.x, a.y, a.z, a.w};
      float bv[4] = {b.x, b.y, b.z, b.w};
#pragma unroll
      for (int i = 0; i < 4; ++i)
#pragma unroll
        for (int j = 0; j < 4; ++j)
          acc[i][j] = fmaf(av[i], bv[j], acc[i][j]);
    }
    __syncthreads();
  }
#pragma unroll
  for (int i = 0; i < 4; ++i) {
    float4 o;
    o.x = acc[i][0] * scale; o.y = acc[i][1] * scale;
    o.z = acc[i][2] * scale; o.w = acc[i][3] * scale;
    *(float4*)(Sb + (size_t)(q0g + ty4 + i) * Sk + k0g + tx4) = o;
  }
}

// ---------------------------------------------------------------------------
// In-place masked softmax over last dim. grid: B*NH*TLEN rows.
// causal=1: self-attn mask = (tgt[b,q] != 0) && (k <= q); causal=0: no mask.
__global__ __launch_bounds__(256) void softmax_mask_kernel(
    float* __restrict__ S, const int* __restrict__ tgt, int Sk, int causal) {
  __shared__ float buf[TLEN];
  __shared__ float red[4];
  int r = blockIdx.x;            // ((b*NH + h)*TLEN + q)
  int q = r & (TLEN - 1);
  int b = r >> 13;               // / (NH*TLEN)
  float* row = S + (size_t)r * Sk;
  int tid = threadIdx.x;
  bool row_valid = true;
  if (causal) row_valid = (tgt[b * TLEN + q] != 0);
  float lmax = -3.4e38f;
  for (int i = tid; i < Sk; i += 256) {
    float v = row[i];
    if (causal && (!row_valid || i > q)) v = -1e9f;
    buf[i] = v;
    lmax = fmaxf(lmax, v);
  }
  float gmax = block_reduce(lmax, 1, red);
  float lsum = 0.f;
  for (int i = tid; i < Sk; i += 256) {
    float e = __expf(buf[i] - gmax);
    buf[i] = e;
    lsum += e;
  }
  float gsum = block_reduce(lsum, 0, red);
  float inv = 1.0f / gsum;
  for (int i = tid; i < Sk; i += 256) row[i] = buf[i] * inv;
}

// ---------------------------------------------------------------------------
// O[b, q, h*64+n] = sum_k P[bh, q, k] * V[b, k, h*64+n]
// grid: (Sq/64, B*NH). N = 64 (one tile).
__global__ __launch_bounds__(256) void attn_pv_kernel(
    const float* __restrict__ P, const float* __restrict__ V,
    float* __restrict__ O, int Sq, int Sk) {
  __shared__ float Ps[16][64];
  __shared__ float Vs[16][64];
  int tid = threadIdx.x;
  int tx4 = (tid & 15) << 2;
  int ty4 = (tid >> 4) << 2;
  int bh = blockIdx.y;
  int b = bh >> 4, h = bh & 15;
  int q0 = blockIdx.x << 6;
  const float* Pb = P + (size_t)bh * Sq * Sk;
  const float* Vb = V + (size_t)b * Sk * Dm + (size_t)h * DK;
  float* Ob = O + (size_t)b * Sq * Dm + (size_t)h * DK;
  int ar = tid >> 2, ac = (tid & 3) << 2;
  int br = tid >> 4;
  float acc[4][4] = {{0.f}};
  for (int k0 = 0; k0 < Sk; k0 += 16) {
    float4 a4 = *(const float4*)(Pb + (size_t)(q0 + ar) * Sk + k0 + ac);
    float4 b4 = *(const float4*)(Vb + (size_t)(k0 + br) * Dm + tx4);
    Ps[ac + 0][ar] = a4.x; Ps[ac + 1][ar] = a4.y;
    Ps[ac + 2][ar] = a4.z; Ps[ac + 3][ar] = a4.w;
    *(float4*)&Vs[br][tx4] = b4;
    __syncthreads();
#pragma unroll
    for (int kk = 0; kk < 16; ++kk) {
      float4 a = *(const float4*)&Ps[kk][ty4];
      float4 b = *(const float4*)&Vs[kk][tx4];
      float av[4] = {a.x, a.y, a.z, a.w};
      float bv[4] = {b.x, b.y, b.z, b.w};
#pragma unroll
      for (int i = 0; i < 4; ++i)
#pragma unroll
        for (int j = 0; j < 4; ++j)
          acc[i][j] = fmaf(av[i], bv[j], acc[i][j]);
    }
    __syncthreads();
  }
#pragma unroll
  for (int i = 0; i < 4; ++i) {
    float4 o;
    o.x = acc[i][0]; o.y = acc[i][1]; o.z = acc[i][2]; o.w = acc[i][3];
    *(float4*)(Ob + (size_t)(q0 + ty4 + i) * Dm + tx4) = o;
  }
}

// ---------------------------------------------------------------------------
// x = LayerNorm(x + a) * g + b   (row = one token, D = 1024)
__global__ __launch_bounds__(256) void add_ln_kernel(
    float* __restrict__ x, const float* __restrict__ a,
    const float* __restrict__ g, const float* __restrict__ be) {
  __shared__ float buf[Dm];
  __shared__ float red[4];
  int r = blockIdx.x;
  float* xr = x + (size_t)r * Dm;
  const float* ar = a + (size_t)r * Dm;
  int tid = threadIdx.x;
  float ls = 0.f;
  for (int i = tid; i < Dm; i += 256) {
    float v = xr[i] + ar[i];
    buf[i] = v;
    ls += v;
  }
  float mu = block_reduce(ls, 0, red) * (1.0f / Dm);
  float lv = 0.f;
  for (int i = tid; i < Dm; i += 256) {
    float d = buf[i] - mu;
    lv += d * d;
  }
  float var = block_reduce(lv, 0, red) * (1.0f / Dm);
  float inv = rsqrtf(var + 1e-5f);
  for (int i = tid; i < Dm; i += 256)
    xr[i] = (buf[i] - mu) * inv * g[i] + be[i];
}

// ---------------------------------------------------------------------------
extern "C" void kernel_launch(void* const* d_in, const int* in_sizes, int n_in,
                              void* d_out, int out_size, void* d_ws, size_t ws_size,
                              hipStream_t stream) {
  // setup_inputs() dict order:
  const float* src  = (const float*)d_in[0];
  const int*   tgt  = (const int*)  d_in[1];
  const float* emb  = (const float*)d_in[2];
  const float* fc_w = (const float*)d_in[3];
  const float* fc_b = (const float*)d_in[4];
  const float* sa_wq = (const float*)d_in[5];
  const float* sa_bq = (const float*)d_in[6];
  const float* sa_wk = (const float*)d_in[7];
  const float* sa_bk = (const float*)d_in[8];
  const float* sa_wv = (const float*)d_in[9];
  const float* sa_bv = (const float*)d_in[10];
  const float* sa_wo = (const float*)d_in[11];
  const float* sa_bo = (const float*)d_in[12];
  const float* ca_wq = (const float*)d_in[13];
  const float* ca_bq = (const float*)d_in[14];
  const float* ca_wk = (const float*)d_in[15];
  const float* ca_bk = (const float*)d_in[16];
  const float* ca_wv = (const float*)d_in[17];
  const float* ca_bv = (const float*)d_in[18];
  const float* ca_wo = (const float*)d_in[19];
  const float* ca_bo = (const float*)d_in[20];
  const float* w1   = (const float*)d_in[21];
  const float* b1   = (const float*)d_in[22];
  const float* w2   = (const float*)d_in[23];
  const float* b2   = (const float*)d_in[24];
  const float* n1g  = (const float*)d_in[25];
  const float* n2g  = (const float*)d_in[26];
  const float* n3g  = (const float*)d_in[27];
  const float* n1b  = (const float*)d_in[28];
  const float* n2b  = (const float*)d_in[29];
  const float* n3b  = (const float*)d_in[30];
  float* out = (float*)d_out;

  // Workspace carve-up (floats)
  float* ws = (float*)d_ws;
  const size_t encN   = (size_t)Bb * SLEN * Dm;   // 1M
  const size_t xN     = (size_t)Bb * TLEN * Dm;   // 2M
  float* enc    = ws;
  float* x      = enc + encN;
  float* qb     = x + xN;
  float* kb     = qb + xN;
  float* vb     = kb + xN;
  float* attnb  = vb + xN;
  float* projb  = attnb + xN;
  float* ffh    = projb + xN;                     // 2048*4096
  float* scores = ffh + (size_t)Bb * TLEN * FFd;  // 4*16*512*512

  const int M  = Bb * TLEN;   // 2048 decoder tokens
  const int Me = Bb * SLEN;   // 1024 encoder tokens
  dim3 blk(256);

  embed_pe_kernel<<<(Bb * TLEN * Dm) / 256, blk, 0, stream>>>(emb, tgt, x);
  src_pe_kernel<<<(Bb * SLEN * Dm) / 256, blk, 0, stream>>>(src, enc);

  const float scale = 0.125f;   // 1/sqrt(64)

  for (int l = 0; l < NL; ++l) {
    const size_t wOff = (size_t)l * Dm * Dm;
    const size_t bOff = (size_t)l * Dm;

    // ---- self attention ----
    gemm3_mfma<<<dim3(Dm / 128, M / 128, 3), blk, 0, stream>>>(
        x, x, x,
        sa_wq + wOff, sa_wk + wOff, sa_wv + wOff,
        sa_bq + bOff, sa_bk + bOff, sa_bv + bOff,
        qb, kb, vb, M, M, M, Dm, Dm);
    attn_scores_kernel<<<dim3(TLEN / 64, TLEN / 64, Bb * NH), blk, 0, stream>>>(
        qb, kb, scores, TLEN, TLEN, scale);
    softmax_mask_kernel<<<Bb * NH * TLEN, blk, 0, stream>>>(scores, tgt, TLEN, 1);
    attn_pv_kernel<<<dim3(TLEN / 64, Bb * NH), blk, 0, stream>>>(
        scores, vb, attnb, TLEN, TLEN);
    // O-projection: BM=64 -> 256 blocks fills the chip
    gemm_mfma_t<64, 1, 4><<<dim3(Dm / 128, M / 64), blk, 0, stream>>>(
        attnb, sa_wo + wOff, sa_bo + bOff, projb, M, Dm, Dm, 0);
    add_ln_kernel<<<M, blk, 0, stream>>>(x, projb, n1g + bOff, n1b + bOff);

    // ---- cross attention ----
    gemm3_mfma<<<dim3(Dm / 128, M / 128, 3), blk, 0, stream>>>(
        x, enc, enc,
        ca_wq + wOff, ca_wk + wOff, ca_wv + wOff,
        ca_bq + bOff, ca_bk + bOff, ca_bv + bOff,
        qb, kb, vb, M, Me, Me, Dm, Dm);
    attn_scores_kernel<<<dim3(SLEN / 64, TLEN / 64, Bb * NH), blk, 0, stream>>>(
        qb, kb, scores, TLEN, SLEN, scale);
    softmax_mask_kernel<<<Bb * NH * TLEN, blk, 0, stream>>>(scores, tgt, SLEN, 0);
    attn_pv_kernel<<<dim3(TLEN / 64, Bb * NH), blk, 0, stream>>>(
        scores, vb, attnb, TLEN, SLEN);
    gemm_mfma_t<64, 1, 4><<<dim3(Dm / 128, M / 64), blk, 0, stream>>>(
        attnb, ca_wo + wOff, ca_bo + bOff, projb, M, Dm, Dm, 0);
    add_ln_kernel<<<M, blk, 0, stream>>>(x, projb, n2g + bOff, n2b + bOff);

    // ---- feed forward ----
    gemm_mfma_t<128, 2, 2><<<dim3(FFd / 128, M / 128), blk, 0, stream>>>(
        x, w1 + (size_t)l * Dm * FFd, b1 + (size_t)l * FFd, ffh, M, FFd, Dm, 1);
    gemm_mfma_t<64, 1, 4><<<dim3(Dm / 128, M / 64), blk, 0, stream>>>(
        ffh, w2 + (size_t)l * FFd * Dm, b2 + bOff, projb, M, Dm, FFd, 0);
    add_ln_kernel<<<M, blk, 0, stream>>>(x, projb, n3g + bOff, n3b + bOff);
  }

  // ---- final projection to vocab ----
  gemm_mfma_t<128, 2, 2><<<dim3(Vv / 128, M / 128), blk, 0, stream>>>(
      x, fc_w, fc_b, out, M, Vv, Dm, 0);
}